// Round 9
// baseline (167.386 us; speedup 1.0000x reference)
//
#include <hip/hip_runtime.h>
#include <math.h>

#define S_ 2048
#define D_ 1024
#define HN_ 1024
#define B_ 4
#define M_ 8192
#define ITERS_ 10
#define DT_ 0.1f
#define PI_ 3.14159265358979323846f
#define TWOPI_ 6.28318530717958647692f
#define INV2PI_ 0.15915494309189533577f
#define SCALE_ 4096.0f
#define INVSC2_ (1.0f / 16777216.0f)   // 2^-24

typedef __attribute__((ext_vector_type(8))) _Float16 f16x8;
typedef __attribute__((ext_vector_type(4))) float f32x4;

// static scratch
__device__ __align__(16) ushort g_xs [(size_t)M_ * 2048];      // x split [a|b] fp16, scaled 4096
__device__ __align__(16) ushort g_WpB[(size_t)64 * 64 * 512];  // Wp frag layout [n16][kt32][l][8]
__device__ __align__(16) ushort g_WoB[(size_t)64 * 32 * 512];  // Wo frag layout [n16][kt32][l][8]
__device__ __align__(16) float  g_ph [(size_t)B_ * HN_ * S_];  // phases f32 [b][hn][s]
__device__ __align__(16) ushort g_phh[(size_t)B_ * HN_ * S_];  // final phases fp16 [b][hn][s]
__device__ __align__(16) ushort g_phT[(size_t)M_ * HN_];       // phases fp16 [(b,s)][hn]

__device__ __forceinline__ ushort f2h(float f) {
    union { _Float16 h; ushort u; } v; v.h = (_Float16)f; return v.u;
}
__device__ __forceinline__ void split2s(float x, ushort& A, ushort& Bc) {
    const float xs = x * SCALE_;
    union { _Float16 h; ushort u; } va, vb;
    va.h = (_Float16)xs;
    const float r = xs - (float)va.h;   // exact
    vb.h = (_Float16)r;
    A = va.u; Bc = vb.u;
}
__device__ __forceinline__ void gload16(const void* g, void* l) {
    __builtin_amdgcn_global_load_lds(
        (const __attribute__((address_space(1))) void*)g,
        (__attribute__((address_space(3))) void*)l, 16, 0, 0);
}
__device__ __forceinline__ int pack2(ushort a, ushort b) {
    return (int)(unsigned)a | ((int)(unsigned)b << 16);
}

// ---------------------------------------------------------------------------
// x [8192][1024] f32 -> g_xs [8192][2048] fp16: [k: a][1024+k: b]
// ---------------------------------------------------------------------------
__global__ __launch_bounds__(256) void split_x(const float* __restrict__ X) {
    const int idx = blockIdx.x * 256 + threadIdx.x;
    const float4 v = ((const float4*)X)[idx];
    const int m  = idx >> 8;
    const int k4 = (idx & 255) * 4;
    ushort a[4], b[4];
    split2s(v.x, a[0], b[0]);
    split2s(v.y, a[1], b[1]);
    split2s(v.z, a[2], b[2]);
    split2s(v.w, a[3], b[3]);
    ushort* row = g_xs + (size_t)m * 2048 + k4;
    int2 oa; oa.x = pack2(a[0], a[1]); oa.y = pack2(a[2], a[3]);
    int2 ob; ob.x = pack2(b[0], b[1]); ob.y = pack2(b[2], b[3]);
    *(int2*)(row)        = oa;
    *(int2*)(row + 1024) = ob;
}

// ---------------------------------------------------------------------------
// Wp [k][n] f32 -> g_WpB frag layout: [n16][kt32][lane][8] fp16 (a: kt32<32,
// b: kt32>=32). value(n16,kt32,l,j) = comp(Wp[(kt32%32)*32+(l>>4)*8+j + k0][n16*16+(l&15)])
// Block: (kc, n16) covers k0=kc*64..+64, 16 n. 128 threads.
// ---------------------------------------------------------------------------
__global__ __launch_bounds__(128) void prep_WpB(const float* __restrict__ Wp) {
    __shared__ float t[64][17];
    const int kc = blockIdx.x, n16 = blockIdx.y;
    const int k0 = kc * 64, nb = n16 * 16;
    {
        const int r = threadIdx.x >> 1, hf = (threadIdx.x & 1) * 8;
        const float* src = Wp + (size_t)(k0 + r) * HN_ + nb + hf;
        *(float4*)&t[r][hf]     = *(const float4*)src;
        *(float4*)&t[r][hf + 4] = *(const float4*)(src + 4);
    }
    __syncthreads();
    const int h = threadIdx.x >> 6, l = threadIdx.x & 63;
    const int n = l & 15, ks8 = (l >> 4) * 8;
    ushort ua[8], ub[8];
    #pragma unroll
    for (int j = 0; j < 8; ++j)
        split2s(t[h * 32 + ks8 + j][n], ua[j], ub[j]);
    const int kt32a = kc * 2 + h;
    ushort* da = g_WpB + ((size_t)(n16 * 64 + kt32a) * 64 + l) * 8;
    ushort* db = g_WpB + ((size_t)(n16 * 64 + 32 + kt32a) * 64 + l) * 8;
    int4 oa, ob;
    oa.x = pack2(ua[0], ua[1]); oa.y = pack2(ua[2], ua[3]);
    oa.z = pack2(ua[4], ua[5]); oa.w = pack2(ua[6], ua[7]);
    ob.x = pack2(ub[0], ub[1]); ob.y = pack2(ub[2], ub[3]);
    ob.z = pack2(ub[4], ub[5]); ob.w = pack2(ub[6], ub[7]);
    *(int4*)da = oa;
    *(int4*)db = ob;
}

// ---------------------------------------------------------------------------
// Wo [hn][d] f32 -> g_WoB frag layout [n16][kt32][lane][8] fp16, K=1024.
// ---------------------------------------------------------------------------
__global__ __launch_bounds__(128) void prep_WoB(const float* __restrict__ Wo) {
    __shared__ float t[64][17];
    const int kc = blockIdx.x, n16 = blockIdx.y;
    const int k0 = kc * 64, nb = n16 * 16;
    {
        const int r = threadIdx.x >> 1, hf = (threadIdx.x & 1) * 8;
        const float* src = Wo + (size_t)(k0 + r) * D_ + nb + hf;
        *(float4*)&t[r][hf]     = *(const float4*)src;
        *(float4*)&t[r][hf + 4] = *(const float4*)(src + 4);
    }
    __syncthreads();
    const int h = threadIdx.x >> 6, l = threadIdx.x & 63;
    const int n = l & 15, ks8 = (l >> 4) * 8;
    ushort u[8];
    #pragma unroll
    for (int j = 0; j < 8; ++j) u[j] = f2h(t[h * 32 + ks8 + j][n]);
    const int kt32 = kc * 2 + h;
    ushort* d = g_WoB + ((size_t)(n16 * 32 + kt32) * 64 + l) * 8;
    int4 o;
    o.x = pack2(u[0], u[1]); o.y = pack2(u[2], u[3]);
    o.z = pack2(u[4], u[5]); o.w = pack2(u[6], u[7]);
    *(int4*)d = o;
}

// ---------------------------------------------------------------------------
// MFMA main loop, BM=128 x BN=128, BK=64, 8 waves (2M x 4N), 512 threads.
// A: LDS-staged (2 x 16KB double buffer, T2 swizzle both-sides, gload16).
// B: DIRECT from L2 into registers via frag-layout coalesced dwordx4 loads,
//    double-buffered in regs (Ba/Bb), covered by the counted vmcnt(6).
// 2 raw s_barriers per K-tile; compiler schedules ds_read/MFMA; 4 waves/SIMD.
// SPLIT: A stored [a|b] (K2=2048), B frag [a|b]; per-tile maps:
//   A byte-off = (t<16 ? t : t-16)*128 ; B kt32 = (t<32 ? 2t : 2t-64).
// ---------------------------------------------------------------------------
template<int NT, int SPLIT>
__device__ __forceinline__ void gemm_mainloop(const ushort* __restrict__ A,
                                              const ushort* __restrict__ Bf,
                                              ushort* lds,
                                              int m0, int n0, int wid, int l,
                                              int wm, int wn,
                                              f32x4 (&acc)[4][2]) {
    constexpr int K2   = SPLIT ? 2048 : 1024;
    constexpr int NK32 = SPLIT ? 64 : 32;
    const int r8   = l >> 3;
    const int swzo = ((l & 7) * 16) ^ (r8 << 4);
    const char* gA = (const char*)(A + (size_t)m0 * K2);
    const int l15 = l & 15;
    const int xk  = (l15 & 7) << 4;
    const int sl0 = (((l >> 4) * 16)) ^ xk;
    const int sl1 = (64 + ((l >> 4) * 16)) ^ xk;
    const char* pA = (const char*)lds + (wm * 64 + l15) * 128;
    const ushort* pB0 = Bf + (size_t)(((n0 >> 4) + wn * 2 + 0) * NK32) * 512 + l * 8;
    const ushort* pB1 = Bf + (size_t)(((n0 >> 4) + wn * 2 + 1) * NK32) * 512 + l * 8;

    #define AOFFB(T) ((size_t)((SPLIT && (T) >= 16) ? (T) - 16 : (T)) * 128)
    #define KT32(T)  ((SPLIT && (T) >= 32) ? 2 * (T) - 64 : 2 * (T))

    #define STAGE_A(T, BUF) do {                                                  \
        const size_t gb_ = AOFFB(T) + swzo;                                       \
        char* lb_ = (char*)lds + (BUF) * 16384 + wid * 2048;                      \
        gload16(gA + (size_t)(wid * 16 + r8)     * (K2 * 2) + gb_, lb_);          \
        gload16(gA + (size_t)(wid * 16 + 8 + r8) * (K2 * 2) + gb_, lb_ + 1024);   \
    } while (0)

    #define LOADB(T, BR) do {                                                     \
        const int kb_ = KT32(T);                                                  \
        BR[0][0] = *(const f16x8*)(pB0 + (size_t)kb_ * 512);                      \
        BR[0][1] = *(const f16x8*)(pB0 + (size_t)(kb_ + 1) * 512);                \
        BR[1][0] = *(const f16x8*)(pB1 + (size_t)kb_ * 512);                      \
        BR[1][1] = *(const f16x8*)(pB1 + (size_t)(kb_ + 1) * 512);                \
    } while (0)

    #define SB __builtin_amdgcn_sched_barrier(0)
    #define LDA(BO) do {                                                          \
        _Pragma("unroll")                                                         \
        for (int i_ = 0; i_ < 4; ++i_) {                                          \
            Aa[i_][0] = *(const f16x8*)(pA + (BO) + i_ * 2048 + sl0);             \
            Aa[i_][1] = *(const f16x8*)(pA + (BO) + i_ * 2048 + sl1);             \
        }                                                                         \
    } while (0)
    #define MFMA_BLK(BR) do {                                                     \
        __builtin_amdgcn_s_setprio(1);                                            \
        _Pragma("unroll")                                                         \
        for (int ks_ = 0; ks_ < 2; ++ks_)                                         \
            _Pragma("unroll")                                                     \
            for (int i_ = 0; i_ < 4; ++i_)                                        \
                _Pragma("unroll")                                                 \
                for (int j_ = 0; j_ < 2; ++j_)                                    \
                    acc[i_][j_] = __builtin_amdgcn_mfma_f32_16x16x32_f16(         \
                        Aa[i_][ks_], BR[j_][ks_], acc[i_][j_], 0, 0, 0);          \
        __builtin_amdgcn_s_setprio(0);                                            \
    } while (0)

    f16x8 Ba[2][2], Bb[2][2];
    f16x8 Aa[4][2];

    LOADB(0, Ba);
    STAGE_A(0, 0);

    for (int t = 0; t < NT; t += 2) {
        // ---- even tile t: buf0, Ba ----
        SB; __builtin_amdgcn_s_barrier(); SB;
        LOADB(t + 1, Bb);
        STAGE_A(t + 1, 1);
        asm volatile("s_waitcnt vmcnt(6)" ::: "memory");
        SB; __builtin_amdgcn_s_barrier(); SB;
        LDA(0);
        MFMA_BLK(Ba);
        // ---- odd tile t+1: buf1, Bb ----
        SB; __builtin_amdgcn_s_barrier(); SB;
        if (t + 2 < NT) {
            LOADB(t + 2, Ba);
            STAGE_A(t + 2, 0);
            asm volatile("s_waitcnt vmcnt(6)" ::: "memory");
        } else {
            asm volatile("s_waitcnt vmcnt(0)" ::: "memory");
        }
        SB; __builtin_amdgcn_s_barrier(); SB;
        LDA(16384);
        MFMA_BLK(Bb);
    }
    #undef STAGE_A
    #undef LOADB
    #undef LDA
    #undef MFMA_BLK
    #undef SB
    #undef AOFFB
    #undef KT32
}

// 512 blocks: per XCD 8 M-panels x 8 N-panels (A fetched once chip-wide)
__device__ __forceinline__ void tile_map(int bid, int& m0, int& n0) {
    const int xcd = bid & 7;
    const int idx = bid >> 3;              // 0..63
    m0 = (xcd * 8 + (idx >> 3)) * 128;     // 64 M-tiles
    n0 = (idx & 7) * 128;                  // 8 N-tiles
}

// GEMM1: g_xs x g_WpB -> pi*tanh(acc*2^-24 + bias) -> g_ph[b][n][s]
__global__ __launch_bounds__(512, 4) void gemm1(const float* __restrict__ bias) {
    __shared__ ushort lds[2 * 8192];   // 32 KB (A only)
    const int tid = threadIdx.x;
    const int wid = tid >> 6, l = tid & 63;
    int m0, n0;
    tile_map(blockIdx.x, m0, n0);
    const int wm = wid >> 2, wn = wid & 3;

    f32x4 acc[4][2];
    #pragma unroll
    for (int i = 0; i < 4; ++i)
        #pragma unroll
        for (int j = 0; j < 2; ++j) acc[i][j] = (f32x4){0.f, 0.f, 0.f, 0.f};

    gemm_mainloop<48, 1>(g_xs, g_WpB, lds, m0, n0, wid, l, wm, wn, acc);

    const int r4 = (l >> 4) * 4;
    const int cn = l & 15;
    #pragma unroll
    for (int i = 0; i < 4; ++i) {
        const int mg = m0 + wm * 64 + i * 16 + r4;
        const int bidx = mg >> 11;
        const int sg = mg & 2047;
        #pragma unroll
        for (int jj = 0; jj < 2; ++jj) {
            const int ng = n0 + wn * 32 + jj * 16 + cn;
            const float bb = bias[ng];
            float4 o;
            o.x = PI_ * tanhf(fmaf(acc[i][jj][0], INVSC2_, bb));
            o.y = PI_ * tanhf(fmaf(acc[i][jj][1], INVSC2_, bb));
            o.z = PI_ * tanhf(fmaf(acc[i][jj][2], INVSC2_, bb));
            o.w = PI_ * tanhf(fmaf(acc[i][jj][3], INVSC2_, bb));
            *(float4*)(g_ph + ((size_t)bidx * HN_ + ng) * S_ + sg) = o;
        }
    }
}

// GEMM3: g_phT x g_WoB + bias -> Y [8192][1024] f32
__global__ __launch_bounds__(512, 4) void gemm3(const float* __restrict__ bias,
                                                float* __restrict__ Y) {
    __shared__ ushort lds[2 * 8192];   // 32 KB
    const int tid = threadIdx.x;
    const int wid = tid >> 6, l = tid & 63;
    int m0, n0;
    tile_map(blockIdx.x, m0, n0);
    const int wm = wid >> 2, wn = wid & 3;

    f32x4 acc[4][2];
    #pragma unroll
    for (int i = 0; i < 4; ++i)
        #pragma unroll
        for (int j = 0; j < 2; ++j) acc[i][j] = (f32x4){0.f, 0.f, 0.f, 0.f};

    gemm_mainloop<16, 0>(g_phT, g_WoB, lds, m0, n0, wid, l, wm, wn, acc);

    const int r4 = (l >> 4) * 4;
    const int cn = l & 15;
    #pragma unroll
    for (int i = 0; i < 4; ++i) {
        const int mg = m0 + wm * 64 + i * 16 + r4;
        #pragma unroll
        for (int jj = 0; jj < 2; ++jj) {
            const int ng = n0 + wn * 32 + jj * 16 + cn;
            const float bb = bias[ng];
            #pragma unroll
            for (int r = 0; r < 4; ++r)
                Y[(size_t)(mg + r) * D_ + ng] = acc[i][jj][r] + bb;
        }
    }
}

// ---------------------------------------------------------------------------
// Kuramoto (unchanged, verified): one wave per (b, hn), 10 iters in registers.
// ---------------------------------------------------------------------------
__global__ __launch_bounds__(256) void kuramoto(const int* __restrict__ mask,
                                                const float* __restrict__ natf,
                                                const float* __restrict__ coup) {
    const int wave = blockIdx.x * 4 + (threadIdx.x >> 6);
    const int lane = threadIdx.x & 63;
    const int b = wave >> 10;
    const int hn = wave & 1023;
    const int h = hn >> 7;

    const float wf = natf[hn];
    const float K = coup[h];

    const float* base = g_ph + ((size_t)b * HN_ + hn) * S_;

    float ph[32];
    #pragma unroll
    for (int i = 0; i < 8; ++i) {
        float4 v = *(const float4*)(base + i * 256 + lane * 4);
        ph[4 * i + 0] = v.x; ph[4 * i + 1] = v.y;
        ph[4 * i + 2] = v.z; ph[4 * i + 3] = v.w;
    }

    const int* mb = mask + b * S_;
    unsigned mbits = 0;
    #pragma unroll
    for (int i = 0; i < 8; ++i) {
        int4 mv = *(const int4*)(mb + i * 256 + lane * 4);
        mbits |= (mv.x != 0 ? 1u : 0u) << (4 * i + 0);
        mbits |= (mv.y != 0 ? 1u : 0u) << (4 * i + 1);
        mbits |= (mv.z != 0 ? 1u : 0u) << (4 * i + 2);
        mbits |= (mv.w != 0 ? 1u : 0u) << (4 * i + 3);
    }

    for (int it = 0; it < ITERS_; ++it) {
        float s[32], c[32];
        float ls = 0.f, lc = 0.f;
        #pragma unroll
        for (int i = 0; i < 32; ++i) {
            s[i] = __sinf(ph[i]);
            c[i] = __cosf(ph[i]);
            const float mf = (float)((mbits >> i) & 1u);
            ls = fmaf(mf, s[i], ls);
            lc = fmaf(mf, c[i], lc);
        }
        #pragma unroll
        for (int off = 32; off; off >>= 1) {
            ls += __shfl_xor(ls, off);
            lc += __shfl_xor(lc, off);
        }
        const float ms = ls * (1.f / 2048.f);
        const float mc = lc * (1.f / 2048.f);
        #pragma unroll
        for (int i = 0; i < 32; ++i) {
            const float dth = fmaf(K, fmaf(s[i], mc, -c[i] * ms), wf);
            float t = fmaf(DT_, dth, ph[i]) + PI_;
            t -= TWOPI_ * floorf(t * INV2PI_);
            ph[i] = t - PI_;
        }
    }

    ushort* ob = g_phh + ((size_t)b * HN_ + hn) * S_;
    #pragma unroll
    for (int i = 0; i < 8; ++i) {
        ushort4 o;
        o.x = f2h(ph[4 * i + 0]); o.y = f2h(ph[4 * i + 1]);
        o.z = f2h(ph[4 * i + 2]); o.w = f2h(ph[4 * i + 3]);
        *(ushort4*)(ob + i * 256 + lane * 4) = o;
    }
}

// ---------------------------------------------------------------------------
// g_phh [b][hn][s] fp16 -> g_phT [(b,s)][hn] fp16  (64x64 tiles, unchanged)
// ---------------------------------------------------------------------------
__global__ __launch_bounds__(256) void transpose_ph() {
    __shared__ ushort t[64][72];
    const int b = blockIdx.z;
    const int h0 = blockIdx.y * 64;
    const int s0 = blockIdx.x * 64;
    const int r = threadIdx.x >> 2;
    const int c = (threadIdx.x & 3) * 16;
    const ushort* src = g_phh + ((size_t)b * HN_ + h0 + r) * S_ + s0 + c;
    *(int4*)&t[r][c] = *(const int4*)src;
    *(int4*)&t[r][c + 8] = *(const int4*)(src + 8);
    __syncthreads();
    ushort o[16];
    #pragma unroll
    for (int j = 0; j < 16; ++j) o[j] = t[c + j][r];
    ushort* dst = g_phT + ((size_t)(b * S_ + s0 + r)) * HN_ + h0 + c;
    int4 o0, o1;
    o0.x = pack2(o[0], o[1]);   o0.y = pack2(o[2], o[3]);
    o0.z = pack2(o[4], o[5]);   o0.w = pack2(o[6], o[7]);
    o1.x = pack2(o[8], o[9]);   o1.y = pack2(o[10], o[11]);
    o1.z = pack2(o[12], o[13]); o1.w = pack2(o[14], o[15]);
    *(int4*)dst = o0;
    *(int4*)(dst + 8) = o1;
}

extern "C" void kernel_launch(void* const* d_in, const int* in_sizes, int n_in,
                              void* d_out, int out_size, void* d_ws, size_t ws_size,
                              hipStream_t stream) {
    const float* x    = (const float*)d_in[0];
    const int*   mask = (const int*)d_in[1];
    const float* Wp   = (const float*)d_in[2];
    const float* bp   = (const float*)d_in[3];
    const float* natf = (const float*)d_in[4];
    const float* coup = (const float*)d_in[5];
    const float* Wo   = (const float*)d_in[6];
    const float* bo   = (const float*)d_in[7];
    float* y = (float*)d_out;

    split_x  <<<dim3(8192),         256, 0, stream>>>(x);
    prep_WpB <<<dim3(16, 64),       128, 0, stream>>>(Wp);
    prep_WoB <<<dim3(16, 64),       128, 0, stream>>>(Wo);
    gemm1    <<<dim3(512),          512, 0, stream>>>(bp);
    kuramoto <<<dim3(1024),         256, 0, stream>>>(mask, natf, coup);
    transpose_ph<<<dim3(32, 16, 4), 256, 0, stream>>>();
    gemm3    <<<dim3(512),          512, 0, stream>>>(bo, y);
}